// Round 4
// baseline (8697.246 us; speedup 1.0000x reference)
//
#include <hip/hip_runtime.h>
#include <hip/hip_cooperative_groups.h>

namespace cg = cooperative_groups;

#define BLK 256

typedef __bf16 bf16;
typedef __bf16 bf16x8 __attribute__((ext_vector_type(8)));
typedef float f32x4 __attribute__((ext_vector_type(4)));

__device__ __forceinline__ float sigm(float x) { return 1.f / (1.f + __expf(-x)); }
__device__ __forceinline__ float tanh_(float x) {
    x = fminf(fmaxf(x, -15.f), 15.f);
    float e = __expf(2.f * x);
    return (e - 1.f) / (e + 1.f);
}

// async 16B global->LDS; lds dest is wave-uniform base (+ lane*16 implicit)
__device__ __forceinline__ void gl2lds(const bf16* g, bf16* l) {
    __builtin_amdgcn_global_load_lds((const __attribute__((address_space(1))) void*)g,
                                     (__attribute__((address_space(3))) void*)l, 16, 0, 0);
}

struct Params {
    const float *src, *tgt, *WH, *bH, *Wk, *Wr, *bl;
    float* out;
    bf16 *srcb, *tgtb, *WHhi, *WHlo, *Wrhi, *Wrlo;
    bf16 *P1, *P2, *P3, *P4, *P5;
    float* bz;
    bf16 *sh, *th;
    float *sc, *tc;
    int nblk;
};

// ================= persistent cooperative kernel =================
__global__ __launch_bounds__(256, 4) void k_all(Params p) {
    cg::grid_group grid = cg::this_grid();
    __shared__ __align__(16) bf16 At[64 * 64];   // 8 KB, 16B-granule XOR swizzle
    __shared__ __align__(16) bf16 Bt[128 * 64];  // 16 KB
    const int t = threadIdx.x, w = t >> 6, l = t & 63;
    const int bid = blockIdx.x;
    const int nblk = p.nblk;
    const int NT = nblk * BLK;
    const int gtid = bid * BLK + t;

    // ---------------- phase 0: prep (casts, transposes, bz) ----------------
    for (int id = gtid; id < 1048576; id += NT) p.srcb[id] = (bf16)p.src[id];
    for (int id = gtid; id < 1048576; id += NT) p.tgtb[id] = (bf16)p.tgt[id];
    for (int id = gtid; id < 524288; id += NT) {
        float v = p.WH[id];
        bf16 h = (bf16)v;
        p.WHhi[id] = h;
        p.WHlo[id] = (bf16)(v - (float)h);
    }
    for (int id = gtid; id < 1048576; id += NT) {  // W_rec^T split
        int c = id >> 9, r = id & 511;
        float v = p.Wr[(size_t)r * 2048 + c];
        bf16 h = (bf16)v;
        p.Wrhi[id] = h;
        p.Wrlo[id] = (bf16)(v - (float)h);
    }
    for (int id = gtid; id < 1048576; id += NT) {  // Wk^T -> P2
        int c = id >> 9, r = id & 511;
        p.P2[id] = (bf16)p.Wk[(size_t)r * 2048 + c];
    }
    for (int id = gtid; id < 2048; id += NT) {  // bz = b_H2h @ W_rec + b_lstm
        float s = p.bl[id];
        for (int k = 0; k < 512; k++) s += p.bH[k] * p.Wr[(size_t)k * 2048 + id];
        p.bz[id] = s;
    }
    __threadfence();
    grid.sync();

    // ---------------- phase 1: P-matrix GEMM, grid-stride over 256 tiles ----
    for (int tile = bid; tile < 256; tile += nblk) {
        const int m0 = (tile >> 3) * 64, n0 = (tile & 7) * 128;
        f32x4 acc[2][4] = {};
        const bf16* Aps[3] = {p.Wrhi, p.Wrlo, p.Wrhi};
        const bf16* Bps[3] = {p.WHhi, p.WHhi, p.WHlo};
        for (int ph = 0; ph < 3; ph++) {
            const bf16* Ap = Aps[ph] + (size_t)m0 * 512;
            const bf16* Bp = Bps[ph] + (size_t)n0 * 512;
            for (int kt = 0; kt < 8; kt++) {
                int k0 = kt * 64;
                __syncthreads();
#pragma unroll
                for (int q = 0; q < 2; q++) {
                    int pp = q * 256 + t;
                    int r = pp >> 3, c = (pp & 7) ^ (r & 7);
                    gl2lds(Ap + (size_t)r * 512 + k0 + c * 8, &At[(q * 256 + w * 64) * 8]);
                }
#pragma unroll
                for (int q = 0; q < 4; q++) {
                    int pp = q * 256 + t;
                    int r = pp >> 3, c = (pp & 7) ^ (r & 7);
                    gl2lds(Bp + (size_t)r * 512 + k0 + c * 8, &Bt[(q * 256 + w * 64) * 8]);
                }
                __syncthreads();
#pragma unroll
                for (int ks = 0; ks < 2; ks++) {
                    int c = ks * 4 + (l >> 4);
                    bf16x8 af[2], bb[4];
#pragma unroll
                    for (int mt = 0; mt < 2; mt++) {
                        int r = (w >> 1) * 32 + mt * 16 + (l & 15);
                        af[mt] = *(const bf16x8*)&At[(r * 8 + (c ^ (r & 7))) * 8];
                    }
#pragma unroll
                    for (int g = 0; g < 4; g++) {
                        int r = g * 32 + (w & 1) * 16 + (l & 15);
                        bb[g] = *(const bf16x8*)&Bt[(r * 8 + (c ^ (r & 7))) * 8];
                    }
#pragma unroll
                    for (int mt = 0; mt < 2; mt++)
#pragma unroll
                        for (int g = 0; g < 4; g++)
                            acc[mt][g] = __builtin_amdgcn_mfma_f32_16x16x32_bf16(
                                af[mt], bb[g], acc[mt][g], 0, 0, 0);
                }
            }
        }
        const bool hihalf = (n0 >= 512);
#pragma unroll
        for (int mt = 0; mt < 2; mt++) {
#pragma unroll
            for (int g = 0; g < 4; g++) {
                int np = n0 + g * 32 + (w & 1) * 16 + (l & 15);
#pragma unroll
                for (int r = 0; r < 4; r++) {
                    int c = m0 + (w >> 1) * 32 + mt * 16 + ((l >> 4) << 2) + r;
                    float v = acc[mt][g][r];
                    if (!hihalf) {
                        p.P4[(size_t)c * 512 + np] = (bf16)v;
                        p.P1[(size_t)c * 512 + np] = (bf16)(v + p.Wk[(size_t)np * 2048 + c]);
                    } else {
                        int kk = np - 512;
                        p.P3[(size_t)c * 512 + kk] = (bf16)v;
                        p.P5[(size_t)c * 512 + kk] = (bf16)(v + p.Wk[(size_t)kk * 2048 + c]);
                    }
                }
            }
        }
    }
    __threadfence();
    grid.sync();

    // ---------------- phase 2: 63 diagonals, grid.sync between ----------------
#pragma unroll 1
    for (int d = 0; d < 63; d++) {
        const int i_lo = d > 31 ? d - 31 : 0;
        const int i_hi = d < 31 ? d : 31;
        const int Kd = i_hi - i_lo + 1;
        const bf16* shR = p.sh + (size_t)(d & 1) * 1048576;
        bf16* shW = p.sh + (size_t)((d + 1) & 1) * 1048576;
        const bf16* thR = p.th + (size_t)(d & 1) * 1048576;
        bf16* thW = p.th + (size_t)((d + 1) & 1) * 1048576;
#pragma unroll 1
        for (int tile = bid; tile < Kd * 32; tile += nblk) {
            const int cell = tile >> 5, sub = tile & 31;
            const int side = sub >> 4, ch0 = (sub & 15) << 5;
            const int i = i_lo + cell, j = d - i;
            const size_t stI = (size_t)i * 64 * 512, stJ = (size_t)j * 64 * 512;

            const bf16* Ah[2];
            const bf16* Wh[2];
            int nh = 0;
            if (side == 0) {  // z_s
                Ah[nh] = (j == 0 ? p.srcb : shR) + stI;
                Wh[nh] = (j == 0 ? p.P2 : p.P1);
                nh++;
                if (i > 0) { Ah[nh] = thR + stJ; Wh[nh] = p.P3; nh++; }
            } else {  // z_t
                if (j > 0) { Ah[nh] = shR + stI; Wh[nh] = p.P4; nh++; }
                Ah[nh] = (i == 0 ? p.tgtb : thR) + stJ;
                Wh[nh] = (i == 0 ? p.P2 : p.P5);
                nh++;
            }

            f32x4 acc[2][4] = {};
            for (int hh = 0; hh < nh; hh++) {
                const bf16* Ap = Ah[hh];
                const bf16* Wp = Wh[hh];
                for (int kt = 0; kt < 8; kt++) {
                    int k0 = kt * 64;
                    __syncthreads();
#pragma unroll
                    for (int q = 0; q < 2; q++) {
                        int pp = q * 256 + t;
                        int r = pp >> 3, c = (pp & 7) ^ (r & 7);
                        gl2lds(Ap + (size_t)r * 512 + k0 + c * 8, &At[(q * 256 + w * 64) * 8]);
                    }
#pragma unroll
                    for (int q = 0; q < 4; q++) {
                        int pp = q * 256 + t;
                        int r = pp >> 3, c = (pp & 7) ^ (r & 7);
                        int g = r >> 5;
                        gl2lds(Wp + (size_t)(g * 512 + ch0 + (r & 31)) * 512 + k0 + c * 8,
                               &Bt[(q * 256 + w * 64) * 8]);
                    }
                    __syncthreads();
#pragma unroll
                    for (int ks = 0; ks < 2; ks++) {
                        int c = ks * 4 + (l >> 4);
                        bf16x8 af[2], bb[4];
#pragma unroll
                        for (int mt = 0; mt < 2; mt++) {
                            int r = (w >> 1) * 32 + mt * 16 + (l & 15);
                            af[mt] = *(const bf16x8*)&At[(r * 8 + (c ^ (r & 7))) * 8];
                        }
#pragma unroll
                        for (int g = 0; g < 4; g++) {
                            int r = g * 32 + (w & 1) * 16 + (l & 15);
                            bb[g] = *(const bf16x8*)&Bt[(r * 8 + (c ^ (r & 7))) * 8];
                        }
#pragma unroll
                        for (int mt = 0; mt < 2; mt++)
#pragma unroll
                            for (int g = 0; g < 4; g++)
                                acc[mt][g] = __builtin_amdgcn_mfma_f32_16x16x32_bf16(
                                    af[mt], bb[g], acc[mt][g], 0, 0, 0);
                    }
                }
            }

            const int h = ch0 + (w & 1) * 16 + (l & 15);
            float bzv[4];
#pragma unroll
            for (int g = 0; g < 4; g++) bzv[g] = p.bz[g * 512 + h];
#pragma unroll
            for (int mt = 0; mt < 2; mt++) {
#pragma unroll
                for (int r = 0; r < 4; r++) {
                    int b = (w >> 1) * 32 + mt * 16 + ((l >> 4) << 2) + r;
                    float zi = acc[mt][0][r] + bzv[0];
                    float zf = acc[mt][1][r] + bzv[1];
                    float zg = acc[mt][2][r] + bzv[2];
                    float zo = acc[mt][3][r] + bzv[3];
                    if (side == 0) {
                        size_t off = stI + (size_t)b * 512 + h;
                        float cold = (j == 0) ? 0.f : p.sc[off];
                        float c2 = sigm(zf) * cold + sigm(zi) * tanh_(zg);
                        float h2 = sigm(zo) * tanh_(c2);
                        p.sc[off] = c2;
                        shW[off] = (bf16)h2;
                        if (j == 31) p.out[off] = h2;  // source_out[i]
                    } else {
                        size_t off = stJ + (size_t)b * 512 + h;
                        float cold = (i == 0) ? 0.f : p.tc[off];
                        float c2 = sigm(zf) * cold + sigm(zi) * tanh_(zg);
                        float h2 = sigm(zo) * tanh_(c2);
                        p.tc[off] = c2;
                        thW[off] = (bf16)h2;
                        if (i == 31) p.out[1048576 + off] = h2;  // t_final[0][j]
                    }
                }
            }
        }
        __threadfence();
        grid.sync();
    }
}

// ================= fallback multi-launch kernels (proven R1 path) =================

__global__ void k_cast(const float* __restrict__ in, bf16* __restrict__ out, int n) {
    int i = blockIdx.x * BLK + threadIdx.x;
    if (i < n) out[i] = (bf16)in[i];
}

__global__ void k_cast2(const float* __restrict__ in, bf16* __restrict__ hi,
                        bf16* __restrict__ lo, int n) {
    int i = blockIdx.x * BLK + threadIdx.x;
    if (i < n) {
        float v = in[i];
        bf16 h = (bf16)v;
        hi[i] = h;
        lo[i] = (bf16)(v - (float)h);
    }
}

__global__ void k_tcast2(const float* __restrict__ in, bf16* __restrict__ hi,
                         bf16* __restrict__ lo, int C) {
    int id = blockIdx.x * BLK + threadIdx.x;
    int c = id >> 9, r = id & 511;
    float v = in[(size_t)r * C + c];
    bf16 h = (bf16)v;
    hi[id] = h;
    if (lo) lo[id] = (bf16)(v - (float)h);
}

__global__ void k_bz(const float* __restrict__ bh, const float* __restrict__ Wr,
                     const float* __restrict__ bl, float* __restrict__ bz) {
    int c = blockIdx.x * BLK + threadIdx.x;
    float s = bl[c];
    for (int k = 0; k < 512; k++) s += bh[k] * Wr[(size_t)k * 2048 + c];
    bz[c] = s;
}

__global__ __launch_bounds__(256, 2) void k_gemmP(
    const bf16* __restrict__ Ahi, const bf16* __restrict__ Alo,
    const bf16* __restrict__ Bhi, const bf16* __restrict__ Blo,
    const float* __restrict__ Wk,
    bf16* __restrict__ P1, bf16* __restrict__ P3,
    bf16* __restrict__ P4, bf16* __restrict__ P5) {
    __shared__ __align__(16) bf16 At[64 * 72];
    __shared__ __align__(16) bf16 Bt[4 * 64 * 72];
    const int t = threadIdx.x, w = t >> 6, l = t & 63;
    const int m0 = (blockIdx.x >> 2) * 64, n0 = (blockIdx.x & 3) * 256;
    f32x4 acc[4][4] = {};
    const bf16* Aps[3] = {Ahi, Alo, Ahi};
    const bf16* Bps[3] = {Bhi, Bhi, Blo};
    for (int p = 0; p < 3; p++) {
        const bf16* Ap = Aps[p] + (size_t)m0 * 512;
        const bf16* Bp = Bps[p];
        for (int kt = 0; kt < 8; kt++) {
            int k0 = kt * 64;
            __syncthreads();
#pragma unroll
            for (int q = 0; q < 2; q++) {
                int idx = q * 256 + t, row = idx >> 3, cc = idx & 7;
                uint4 v = *(const uint4*)(Ap + (size_t)row * 512 + k0 + cc * 8);
                *(uint4*)&At[row * 72 + cc * 8] = v;
            }
#pragma unroll
            for (int q = 0; q < 8; q++) {
                int idx = q * 256 + t, g = idx >> 9, rr = (idx >> 3) & 63, cc = idx & 7;
                uint4 v = *(const uint4*)(Bp + (size_t)(n0 + g * 64 + rr) * 512 + k0 + cc * 8);
                *(uint4*)&Bt[(g * 64 + rr) * 72 + cc * 8] = v;
            }
            __syncthreads();
#pragma unroll
            for (int ks = 0; ks < 2; ks++) {
                int ko = ks * 32 + (l >> 4) * 8;
                bf16x8 af[4], bb[4];
#pragma unroll
                for (int mt = 0; mt < 4; mt++)
                    af[mt] = *(const bf16x8*)&At[(mt * 16 + (l & 15)) * 72 + ko];
#pragma unroll
                for (int g = 0; g < 4; g++)
                    bb[g] = *(const bf16x8*)&Bt[(g * 64 + w * 16 + (l & 15)) * 72 + ko];
#pragma unroll
                for (int mt = 0; mt < 4; mt++)
#pragma unroll
                    for (int g = 0; g < 4; g++)
                        acc[mt][g] = __builtin_amdgcn_mfma_f32_16x16x32_bf16(
                            af[mt], bb[g], acc[mt][g], 0, 0, 0);
            }
        }
    }
    const bool hihalf = (n0 >= 512);
#pragma unroll
    for (int mt = 0; mt < 4; mt++) {
#pragma unroll
        for (int g = 0; g < 4; g++) {
            int np = n0 + g * 64 + w * 16 + (l & 15);
#pragma unroll
            for (int r = 0; r < 4; r++) {
                int c = m0 + mt * 16 + ((l >> 4) << 2) + r;
                float v = acc[mt][g][r];
                if (!hihalf) {
                    P4[(size_t)c * 512 + np] = (bf16)v;
                    P1[(size_t)c * 512 + np] = (bf16)(v + Wk[(size_t)np * 2048 + c]);
                } else {
                    int kk = np - 512;
                    P3[(size_t)c * 512 + kk] = (bf16)v;
                    P5[(size_t)c * 512 + kk] = (bf16)(v + Wk[(size_t)kk * 2048 + c]);
                }
            }
        }
    }
}

__global__ __launch_bounds__(256, 4) void k_diag(
    int d, int i_lo,
    const bf16* __restrict__ srcb, const bf16* __restrict__ tgtb,
    const bf16* __restrict__ P1, const bf16* __restrict__ P2,
    const bf16* __restrict__ P3, const bf16* __restrict__ P4,
    const bf16* __restrict__ P5,
    const float* __restrict__ bz,
    const bf16* __restrict__ shR, bf16* __restrict__ shW,
    const bf16* __restrict__ thR, bf16* __restrict__ thW,
    float* __restrict__ sc, float* __restrict__ tc,
    float* __restrict__ out) {
    __shared__ __align__(16) bf16 At[64 * 64];
    __shared__ __align__(16) bf16 Bt[128 * 64];
    const int t = threadIdx.x, w = t >> 6, l = t & 63;
    const int cell = blockIdx.x >> 5, sub = blockIdx.x & 31;
    const int side = sub >> 4, ch0 = (sub & 15) << 5;
    const int i = i_lo + cell, j = d - i;
    const size_t stI = (size_t)i * 64 * 512, stJ = (size_t)j * 64 * 512;

    const bf16* Ah[2];
    const bf16* Wh[2];
    int nh = 0;
    if (side == 0) {
        Ah[nh] = (j == 0 ? srcb : shR) + stI;
        Wh[nh] = (j == 0 ? P2 : P1);
        nh++;
        if (i > 0) { Ah[nh] = thR + stJ; Wh[nh] = P3; nh++; }
    } else {
        if (j > 0) { Ah[nh] = shR + stI; Wh[nh] = P4; nh++; }
        Ah[nh] = (i == 0 ? tgtb : thR) + stJ;
        Wh[nh] = (i == 0 ? P2 : P5);
        nh++;
    }

    f32x4 acc[2][4] = {};
    for (int hh = 0; hh < nh; hh++) {
        const bf16* Ap = Ah[hh];
        const bf16* Wp = Wh[hh];
        for (int kt = 0; kt < 8; kt++) {
            int k0 = kt * 64;
            __syncthreads();
#pragma unroll
            for (int q = 0; q < 2; q++) {
                int pp = q * 256 + t;
                int r = pp >> 3, c = (pp & 7) ^ (r & 7);
                gl2lds(Ap + (size_t)r * 512 + k0 + c * 8, &At[(q * 256 + w * 64) * 8]);
            }
#pragma unroll
            for (int q = 0; q < 4; q++) {
                int pp = q * 256 + t;
                int r = pp >> 3, c = (pp & 7) ^ (r & 7);
                int g = r >> 5;
                gl2lds(Wp + (size_t)(g * 512 + ch0 + (r & 31)) * 512 + k0 + c * 8,
                       &Bt[(q * 256 + w * 64) * 8]);
            }
            __syncthreads();
#pragma unroll
            for (int ks = 0; ks < 2; ks++) {
                int c = ks * 4 + (l >> 4);
                bf16x8 af[2], bb[4];
#pragma unroll
                for (int mt = 0; mt < 2; mt++) {
                    int r = (w >> 1) * 32 + mt * 16 + (l & 15);
                    af[mt] = *(const bf16x8*)&At[(r * 8 + (c ^ (r & 7))) * 8];
                }
#pragma unroll
                for (int g = 0; g < 4; g++) {
                    int r = g * 32 + (w & 1) * 16 + (l & 15);
                    bb[g] = *(const bf16x8*)&Bt[(r * 8 + (c ^ (r & 7))) * 8];
                }
#pragma unroll
                for (int mt = 0; mt < 2; mt++)
#pragma unroll
                    for (int g = 0; g < 4; g++)
                        acc[mt][g] = __builtin_amdgcn_mfma_f32_16x16x32_bf16(
                            af[mt], bb[g], acc[mt][g], 0, 0, 0);
            }
        }
    }

    const int h = ch0 + (w & 1) * 16 + (l & 15);
    float bzv[4];
#pragma unroll
    for (int g = 0; g < 4; g++) bzv[g] = bz[g * 512 + h];
#pragma unroll
    for (int mt = 0; mt < 2; mt++) {
#pragma unroll
        for (int r = 0; r < 4; r++) {
            int b = (w >> 1) * 32 + mt * 16 + ((l >> 4) << 2) + r;
            float zi = acc[mt][0][r] + bzv[0];
            float zf = acc[mt][1][r] + bzv[1];
            float zg = acc[mt][2][r] + bzv[2];
            float zo = acc[mt][3][r] + bzv[3];
            if (side == 0) {
                size_t off = stI + (size_t)b * 512 + h;
                float cold = (j == 0) ? 0.f : sc[off];
                float c2 = sigm(zf) * cold + sigm(zi) * tanh_(zg);
                float h2 = sigm(zo) * tanh_(c2);
                sc[off] = c2;
                shW[off] = (bf16)h2;
                if (j == 31) out[off] = h2;
            } else {
                size_t off = stJ + (size_t)b * 512 + h;
                float cold = (i == 0) ? 0.f : tc[off];
                float c2 = sigm(zf) * cold + sigm(zi) * tanh_(zg);
                float h2 = sigm(zo) * tanh_(c2);
                tc[off] = c2;
                thW[off] = (bf16)h2;
                if (i == 31) out[1048576 + off] = h2;
            }
        }
    }
}

// ================= host =================

extern "C" void kernel_launch(void* const* d_in, const int* in_sizes, int n_in,
                              void* d_out, int out_size, void* d_ws, size_t ws_size,
                              hipStream_t stream) {
    char* w = (char*)d_ws;
    const size_t MB = 1u << 20;
    Params p;
    p.src = (const float*)d_in[0];
    p.tgt = (const float*)d_in[1];
    p.WH = (const float*)d_in[2];
    p.bH = (const float*)d_in[3];
    p.Wk = (const float*)d_in[4];
    p.Wr = (const float*)d_in[5];
    p.bl = (const float*)d_in[6];
    p.out = (float*)d_out;
    p.srcb = (bf16*)(w + 0 * MB);
    p.tgtb = (bf16*)(w + 2 * MB);
    p.WHhi = (bf16*)(w + 4 * MB);
    p.WHlo = (bf16*)(w + 5 * MB);
    p.Wrhi = (bf16*)(w + 6 * MB);
    p.Wrlo = (bf16*)(w + 8 * MB);
    p.P1 = (bf16*)(w + 10 * MB);
    p.P2 = (bf16*)(w + 12 * MB);
    p.P3 = (bf16*)(w + 14 * MB);
    p.P4 = (bf16*)(w + 16 * MB);
    p.P5 = (bf16*)(w + 18 * MB);
    p.bz = (float*)(w + 20 * MB);
    p.sh = (bf16*)(w + 21 * MB);
    p.th = (bf16*)(w + 25 * MB);
    p.sc = (float*)(w + 29 * MB);
    p.tc = (float*)(w + 33 * MB);

    // host-side occupancy query (capture-safe: no stream/device work)
    int dev = 0;
    hipGetDevice(&dev);
    int numCU = 0;
    hipDeviceGetAttribute(&numCU, hipDeviceAttributeMultiprocessorCount, dev);
    int occ = 0;
    hipOccupancyMaxActiveBlocksPerMultiprocessor(&occ, (const void*)k_all, BLK, 0);
    int nblk = occ * numCU;
    if (nblk > 1024) nblk = 1024;
    p.nblk = nblk;

    hipError_t err = hipErrorUnknown;
    if (nblk >= 256) {
        void* args[] = {&p};
        err = hipLaunchCooperativeKernel((void*)k_all, dim3(nblk), dim3(BLK), args, 0, stream);
    }
    if (err != hipSuccess) {
        // ---- fallback: proven multi-launch path ----
        k_cast<<<4096, BLK, 0, stream>>>(p.src, p.srcb, 1048576);
        k_cast<<<4096, BLK, 0, stream>>>(p.tgt, p.tgtb, 1048576);
        k_cast2<<<2048, BLK, 0, stream>>>(p.WH, p.WHhi, p.WHlo, 524288);
        k_tcast2<<<4096, BLK, 0, stream>>>(p.Wr, p.Wrhi, p.Wrlo, 2048);
        k_tcast2<<<4096, BLK, 0, stream>>>(p.Wk, p.P2, nullptr, 2048);
        k_bz<<<8, BLK, 0, stream>>>(p.bH, p.Wr, p.bl, p.bz);
        k_gemmP<<<128, BLK, 0, stream>>>(p.Wrhi, p.Wrlo, p.WHhi, p.WHlo, p.Wk,
                                         p.P1, p.P3, p.P4, p.P5);
        for (int d = 0; d < 63; d++) {
            int i_lo = d > 31 ? d - 31 : 0;
            int i_hi = d < 31 ? d : 31;
            int Kd = i_hi - i_lo + 1;
            const bf16* shR = p.sh + (size_t)(d & 1) * 1048576;
            bf16* shW = p.sh + (size_t)((d + 1) & 1) * 1048576;
            const bf16* thR = p.th + (size_t)(d & 1) * 1048576;
            bf16* thW = p.th + (size_t)((d + 1) & 1) * 1048576;
            k_diag<<<Kd * 32, BLK, 0, stream>>>(d, i_lo, p.srcb, p.tgtb, p.P1, p.P2,
                                                p.P3, p.P4, p.P5, p.bz, shR, shW,
                                                thR, thW, p.sc, p.tc, p.out);
        }
    }
}

// Round 5
// 2569.729 us; speedup vs baseline: 3.3845x; 3.3845x over previous
//
#include <hip/hip_runtime.h>

#define BLK 256

typedef __bf16 bf16;
typedef __bf16 bf16x8 __attribute__((ext_vector_type(8)));
typedef float f32x4 __attribute__((ext_vector_type(4)));
typedef unsigned long long u64;

__device__ __forceinline__ float sigm(float x) { return 1.f / (1.f + __expf(-x)); }
__device__ __forceinline__ float tanh_(float x) {
    x = fminf(fmaxf(x, -15.f), 15.f);
    float e = __expf(2.f * x);
    return (e - 1.f) / (e + 1.f);
}

// async 16B global->LDS; lds dest is wave-uniform base (+ lane*16 implicit)
__device__ __forceinline__ void gl2lds(const bf16* g, bf16* l) {
    __builtin_amdgcn_global_load_lds((const __attribute__((address_space(1))) void*)g,
                                     (__attribute__((address_space(3))) void*)l, 16, 0, 0);
}

#define ALOAD64(p) __hip_atomic_load((const u64*)(p), __ATOMIC_RELAXED, __HIP_MEMORY_SCOPE_AGENT)
#define ALOADF(p) __hip_atomic_load((const float*)(p), __ATOMIC_RELAXED, __HIP_MEMORY_SCOPE_AGENT)
#define ASTOREF(p, v) __hip_atomic_store((float*)(p), (v), __ATOMIC_RELAXED, __HIP_MEMORY_SCOPE_AGENT)
#define ASTOREU(p, v) __hip_atomic_store((unsigned int*)(p), (v), __ATOMIC_RELAXED, __HIP_MEMORY_SCOPE_AGENT)

// ---------------- prep: casts, transposes, bz, flag zeroing ----------------
__global__ void k_prep(const float* __restrict__ src, const float* __restrict__ tgt,
                       const float* __restrict__ WH, const float* __restrict__ bH,
                       const float* __restrict__ Wk, const float* __restrict__ Wr,
                       const float* __restrict__ bl,
                       bf16* __restrict__ srcb, bf16* __restrict__ tgtb,
                       bf16* __restrict__ WHhi, bf16* __restrict__ WHlo,
                       bf16* __restrict__ Wrhi, bf16* __restrict__ Wrlo,
                       bf16* __restrict__ P2, float* __restrict__ bz,
                       int* __restrict__ cellDone) {
    const int gtid = blockIdx.x * BLK + threadIdx.x;
    const int NT = gridDim.x * BLK;
    for (int id = gtid; id < 1048576; id += NT) srcb[id] = (bf16)src[id];
    for (int id = gtid; id < 1048576; id += NT) tgtb[id] = (bf16)tgt[id];
    for (int id = gtid; id < 524288; id += NT) {
        float v = WH[id];
        bf16 h = (bf16)v;
        WHhi[id] = h;
        WHlo[id] = (bf16)(v - (float)h);
    }
    for (int id = gtid; id < 1048576; id += NT) {  // W_rec^T split
        int c = id >> 9, r = id & 511;
        float v = Wr[(size_t)r * 2048 + c];
        bf16 h = (bf16)v;
        Wrhi[id] = h;
        Wrlo[id] = (bf16)(v - (float)h);
    }
    for (int id = gtid; id < 1048576; id += NT) {  // Wk^T -> P2
        int c = id >> 9, r = id & 511;
        P2[id] = (bf16)Wk[(size_t)r * 2048 + c];
    }
    for (int id = gtid; id < 2048; id += NT) {  // bz = b_H2h @ W_rec + b_lstm
        float s = bl[id];
        for (int k = 0; k < 512; k++) s += bH[k] * Wr[(size_t)k * 2048 + id];
        bz[id] = s;
    }
    for (int id = gtid; id < 1024; id += NT) cellDone[id] = 0;
}

// ---------------- P-matrix builder GEMM (proven R1 version) ----------------
__global__ __launch_bounds__(256, 2) void k_gemmP(
    const bf16* __restrict__ Ahi, const bf16* __restrict__ Alo,
    const bf16* __restrict__ Bhi, const bf16* __restrict__ Blo,
    const float* __restrict__ Wk,
    bf16* __restrict__ P1, bf16* __restrict__ P3,
    bf16* __restrict__ P4, bf16* __restrict__ P5) {
    __shared__ __align__(16) bf16 At[64 * 72];
    __shared__ __align__(16) bf16 Bt[4 * 64 * 72];
    const int t = threadIdx.x, w = t >> 6, l = t & 63;
    const int m0 = (blockIdx.x >> 2) * 64, n0 = (blockIdx.x & 3) * 256;
    f32x4 acc[4][4] = {};
    const bf16* Aps[3] = {Ahi, Alo, Ahi};
    const bf16* Bps[3] = {Bhi, Bhi, Blo};
    for (int p = 0; p < 3; p++) {
        const bf16* Ap = Aps[p] + (size_t)m0 * 512;
        const bf16* Bp = Bps[p];
        for (int kt = 0; kt < 8; kt++) {
            int k0 = kt * 64;
            __syncthreads();
#pragma unroll
            for (int q = 0; q < 2; q++) {
                int idx = q * 256 + t, row = idx >> 3, cc = idx & 7;
                uint4 v = *(const uint4*)(Ap + (size_t)row * 512 + k0 + cc * 8);
                *(uint4*)&At[row * 72 + cc * 8] = v;
            }
#pragma unroll
            for (int q = 0; q < 8; q++) {
                int idx = q * 256 + t, g = idx >> 9, rr = (idx >> 3) & 63, cc = idx & 7;
                uint4 v = *(const uint4*)(Bp + (size_t)(n0 + g * 64 + rr) * 512 + k0 + cc * 8);
                *(uint4*)&Bt[(g * 64 + rr) * 72 + cc * 8] = v;
            }
            __syncthreads();
#pragma unroll
            for (int ks = 0; ks < 2; ks++) {
                int ko = ks * 32 + (l >> 4) * 8;
                bf16x8 af[4], bb[4];
#pragma unroll
                for (int mt = 0; mt < 4; mt++)
                    af[mt] = *(const bf16x8*)&At[(mt * 16 + (l & 15)) * 72 + ko];
#pragma unroll
                for (int g = 0; g < 4; g++)
                    bb[g] = *(const bf16x8*)&Bt[(g * 64 + w * 16 + (l & 15)) * 72 + ko];
#pragma unroll
                for (int mt = 0; mt < 4; mt++)
#pragma unroll
                    for (int g = 0; g < 4; g++)
                        acc[mt][g] = __builtin_amdgcn_mfma_f32_16x16x32_bf16(
                            af[mt], bb[g], acc[mt][g], 0, 0, 0);
            }
        }
    }
    const bool hihalf = (n0 >= 512);
#pragma unroll
    for (int mt = 0; mt < 4; mt++) {
#pragma unroll
        for (int g = 0; g < 4; g++) {
            int np = n0 + g * 64 + w * 16 + (l & 15);
#pragma unroll
            for (int r = 0; r < 4; r++) {
                int c = m0 + mt * 16 + ((l >> 4) << 2) + r;
                float v = acc[mt][g][r];
                if (!hihalf) {
                    P4[(size_t)c * 512 + np] = (bf16)v;
                    P1[(size_t)c * 512 + np] = (bf16)(v + Wk[(size_t)np * 2048 + c]);
                } else {
                    int kk = np - 512;
                    P3[(size_t)c * 512 + kk] = (bf16)v;
                    P5[(size_t)c * 512 + kk] = (bf16)(v + Wk[(size_t)kk * 2048 + c]);
                }
            }
        }
    }
}

// ---------------- persistent dataflow wavefront kernel ----------------
struct WaveP {
    const bf16 *srcb, *tgtb, *P1, *P2, *P3, *P4, *P5;
    const float* bz;
    bf16 *sh, *th;
    float *sc, *tc;
    float* out;
    int* cellDone;
    int nblk;
};

__global__ __launch_bounds__(256, 4) void k_wave(WaveP p) {
    __shared__ __align__(16) bf16 Bt[128 * 64];  // 16 KB, XOR-swizzled
    const int t = threadIdx.x, w = t >> 6, l = t & 63;
    const int bid = blockIdx.x;
    const int nblk = p.nblk;

    int J = bid, base = 0;
#pragma unroll 1
    for (int d = 0; d < 63; d++) {
        const int i_lo = d > 31 ? d - 31 : 0;
        const int Kd = d < 32 ? d + 1 : 63 - d;
        const int cnt = Kd * 32;
#pragma unroll 1
        while (J - base < cnt) {
            const int tile = J - base;
            const int cell = tile >> 5, sub = tile & 31;
            const int side = sub >> 4, ch0 = (sub & 15) << 5;
            const int i = i_lo + cell, j = d - i;
            const size_t stI = (size_t)i * 64 * 512, stJ = (size_t)j * 64 * 512;

            // dataflow wait: producers are cells (i,j-1) and (i-1,j)
            if (t == 0) {
                if (j > 0)
                    while (__hip_atomic_load(&p.cellDone[i * 32 + j - 1], __ATOMIC_RELAXED,
                                             __HIP_MEMORY_SCOPE_AGENT) < 32)
                        __builtin_amdgcn_s_sleep(4);
                if (i > 0)
                    while (__hip_atomic_load(&p.cellDone[(i - 1) * 32 + j], __ATOMIC_RELAXED,
                                             __HIP_MEMORY_SCOPE_AGENT) < 32)
                        __builtin_amdgcn_s_sleep(4);
            }
            __syncthreads();

            const bf16* shR = p.sh + (size_t)(d & 1) * 1048576;
            bf16* shW = p.sh + (size_t)((d + 1) & 1) * 1048576;
            const bf16* thR = p.th + (size_t)(d & 1) * 1048576;
            bf16* thW = p.th + (size_t)((d + 1) & 1) * 1048576;

            const bf16* Ah[2];
            const bf16* Wh[2];
            int nh = 0;
            if (side == 0) {  // z_s
                Ah[nh] = (j == 0 ? p.srcb : shR) + stI;
                Wh[nh] = (j == 0 ? p.P2 : p.P1);
                nh++;
                if (i > 0) { Ah[nh] = thR + stJ; Wh[nh] = p.P3; nh++; }
            } else {  // z_t
                if (j > 0) { Ah[nh] = shR + stI; Wh[nh] = p.P4; nh++; }
                Ah[nh] = (i == 0 ? p.tgtb : thR) + stJ;
                Wh[nh] = (i == 0 ? p.P2 : p.P5);
                nh++;
            }

            // wave w owns M-rows [w*16, w*16+16) and all 128 N columns
            f32x4 acc[8] = {};
            for (int hh = 0; hh < nh; hh++) {
                const bf16* Ap = Ah[hh];
                const bf16* Wp = Wh[hh];
                for (int kt = 0; kt < 8; kt++) {
                    int k0 = kt * 64;
                    __syncthreads();
                    // B tile DMA: 128 rows x 64 K, swizzled
#pragma unroll
                    for (int q = 0; q < 4; q++) {
                        int pp = q * 256 + t;
                        int r = pp >> 3, c = (pp & 7) ^ (r & 7);
                        int g = r >> 5;
                        gl2lds(Wp + (size_t)(g * 512 + ch0 + (r & 31)) * 512 + k0 + c * 8,
                               &Bt[(q * 256 + w * 64) * 8]);
                    }
                    // A fragments: direct global->reg, agent-scope (coherent) loads
                    u64 areg[2][2];
                    {
                        const int r = w * 16 + (l & 15);
                        const u64* Ap64 = (const u64*)Ap + (size_t)r * 128;
#pragma unroll
                        for (int ks = 0; ks < 2; ks++) {
                            int ko = k0 + ks * 32 + (l >> 4) * 8;
                            areg[ks][0] = ALOAD64(Ap64 + (ko >> 2));
                            areg[ks][1] = ALOAD64(Ap64 + (ko >> 2) + 1);
                        }
                    }
                    __syncthreads();
#pragma unroll
                    for (int ks = 0; ks < 2; ks++) {
                        int c = ks * 4 + (l >> 4);
                        union { u64 u[2]; bf16x8 v; } cv;
                        cv.u[0] = areg[ks][0];
                        cv.u[1] = areg[ks][1];
                        bf16x8 af = cv.v;
#pragma unroll
                        for (int g8 = 0; g8 < 8; g8++) {
                            int r = g8 * 16 + (l & 15);
                            bf16x8 bb = *(const bf16x8*)&Bt[(r * 8 + (c ^ (r & 7))) * 8];
                            acc[g8] = __builtin_amdgcn_mfma_f32_16x16x32_bf16(af, bb, acc[g8], 0, 0, 0);
                        }
                    }
                }
            }

            // epilogue: lane holds all 4 gates for h = ch0 + hh16*16 + (l&15)
            union { bf16 b; unsigned short s; } c0, c1;
#pragma unroll
            for (int hh16 = 0; hh16 < 2; hh16++) {
                const int h = ch0 + hh16 * 16 + (l & 15);
                float bzv[4];
#pragma unroll
                for (int g = 0; g < 4; g++) bzv[g] = p.bz[g * 512 + h];
#pragma unroll
                for (int r = 0; r < 4; r++) {
                    int b = w * 16 + ((l >> 4) << 2) + r;
                    float zi = acc[0 * 2 + hh16][r] + bzv[0];
                    float zf = acc[1 * 2 + hh16][r] + bzv[1];
                    float zg = acc[2 * 2 + hh16][r] + bzv[2];
                    float zo = acc[3 * 2 + hh16][r] + bzv[3];
                    size_t off = (side == 0 ? stI : stJ) + (size_t)b * 512 + h;
                    float cold;
                    if (side == 0)
                        cold = (j == 0) ? 0.f : ALOADF(&p.sc[off]);
                    else
                        cold = (i == 0) ? 0.f : ALOADF(&p.tc[off]);
                    float c2 = sigm(zf) * cold + sigm(zi) * tanh_(zg);
                    float h2 = sigm(zo) * tanh_(c2);
                    if (side == 0)
                        ASTOREF(&p.sc[off], c2);
                    else
                        ASTOREF(&p.tc[off], c2);
                    // pack bf16 pair (h even/odd via lane parity) -> one 4B coherent store
                    float hp = __shfl_xor(h2, 1);
                    c0.b = (bf16)h2;
                    c1.b = (bf16)hp;
                    unsigned int packed = (unsigned int)c0.s | ((unsigned int)c1.s << 16);
                    if (!(l & 1)) {
                        bf16* hw = (side == 0 ? shW : thW);
                        ASTOREU(&hw[off], packed);
                    }
                    if (side == 0) {
                        if (j == 31) p.out[off] = h2;  // source_out[i]
                    } else if (i == 31) {
                        p.out[1048576 + off] = h2;  // t_final[0][j]
                    }
                }
            }

            __syncthreads();  // all waves' coherent stores drained (vmcnt0) before flag
            if (t == 0)
                __hip_atomic_fetch_add(&p.cellDone[i * 32 + j], 1, __ATOMIC_RELAXED,
                                       __HIP_MEMORY_SCOPE_AGENT);
            J += nblk;
        }
        base += cnt;
    }
}

// ---------------- host ----------------

extern "C" void kernel_launch(void* const* d_in, const int* in_sizes, int n_in,
                              void* d_out, int out_size, void* d_ws, size_t ws_size,
                              hipStream_t stream) {
    char* w = (char*)d_ws;
    const size_t MB = 1u << 20;
    const float* src = (const float*)d_in[0];
    const float* tgt = (const float*)d_in[1];
    const float* WH = (const float*)d_in[2];
    const float* bH = (const float*)d_in[3];
    const float* Wk = (const float*)d_in[4];
    const float* Wr = (const float*)d_in[5];
    const float* bl = (const float*)d_in[6];

    bf16* srcb = (bf16*)(w + 0 * MB);
    bf16* tgtb = (bf16*)(w + 2 * MB);
    bf16* WHhi = (bf16*)(w + 4 * MB);
    bf16* WHlo = (bf16*)(w + 5 * MB);
    bf16* Wrhi = (bf16*)(w + 6 * MB);
    bf16* Wrlo = (bf16*)(w + 8 * MB);
    bf16* P1 = (bf16*)(w + 10 * MB);
    bf16* P2 = (bf16*)(w + 12 * MB);
    bf16* P3 = (bf16*)(w + 14 * MB);
    bf16* P4 = (bf16*)(w + 16 * MB);
    bf16* P5 = (bf16*)(w + 18 * MB);
    float* bz = (float*)(w + 20 * MB);
    bf16* sh = (bf16*)(w + 21 * MB);
    bf16* th = (bf16*)(w + 25 * MB);
    float* sc = (float*)(w + 29 * MB);
    float* tc = (float*)(w + 33 * MB);
    int* cellDone = (int*)(w + 37 * MB);  // [1024]

    k_prep<<<2048, BLK, 0, stream>>>(src, tgt, WH, bH, Wk, Wr, bl, srcb, tgtb,
                                     WHhi, WHlo, Wrhi, Wrlo, P2, bz, cellDone);
    k_gemmP<<<128, BLK, 0, stream>>>(Wrhi, Wrlo, WHhi, WHlo, Wk, P1, P3, P4, P5);

    WaveP p;
    p.srcb = srcb; p.tgtb = tgtb;
    p.P1 = P1; p.P2 = P2; p.P3 = P3; p.P4 = P4; p.P5 = P5;
    p.bz = bz; p.sh = sh; p.th = th; p.sc = sc; p.tc = tc;
    p.out = (float*)d_out;
    p.cellDone = cellDone;

    int dev = 0;
    hipGetDevice(&dev);
    int numCU = 0;
    hipDeviceGetAttribute(&numCU, hipDeviceAttributeMultiprocessorCount, dev);
    int occ = 0;
    hipOccupancyMaxActiveBlocksPerMultiprocessor(&occ, (const void*)k_wave, BLK, 0);
    int nblk = occ * numCU;
    if (nblk > 1024) nblk = 1024;
    if (nblk < 1) nblk = 1;
    p.nblk = nblk;

    void* args[] = {&p};
    hipError_t err =
        hipLaunchCooperativeKernel((void*)k_wave, dim3(nblk), dim3(BLK), args, 0, stream);
    if (err != hipSuccess) {
        // plain launch: grid fits residency by construction (occupancy-derived)
        k_wave<<<nblk, BLK, 0, stream>>>(p);
    }
}

// Round 6
// 2512.512 us; speedup vs baseline: 3.4616x; 1.0228x over previous
//
#include <hip/hip_runtime.h>

#define BLK 256

typedef __bf16 bf16;
typedef __bf16 bf16x8 __attribute__((ext_vector_type(8)));
typedef float f32x4 __attribute__((ext_vector_type(4)));

__device__ __forceinline__ float sigm(float x) { return 1.f / (1.f + __expf(-x)); }
__device__ __forceinline__ float tanh_(float x) {
    x = fminf(fmaxf(x, -15.f), 15.f);
    float e = __expf(2.f * x);
    return (e - 1.f) / (e + 1.f);
}

// async 16B global->LDS; lds dest is wave-uniform base (+ lane*16 implicit)
__device__ __forceinline__ void gl2lds(const bf16* g, bf16* l) {
    __builtin_amdgcn_global_load_lds((const __attribute__((address_space(1))) void*)g,
                                     (__attribute__((address_space(3))) void*)l, 16, 0, 0);
}

// ---------------- fused prep: tiled transposes + casts + bz ----------------
// bid<256: Wr [512][2048] -> WrT split hi/lo [2048][512]
// bid<512: Wk [512][2048] -> P2 [2048][512]
// bid<520: bz[c] = b_H2h @ W_rec + b_lstm
// else:    elementwise casts (srcb, tgtb, WH split)
__global__ __launch_bounds__(256) void k_prep(
    const float* __restrict__ src, const float* __restrict__ tgt,
    const float* __restrict__ WH, const float* __restrict__ bH,
    const float* __restrict__ Wk, const float* __restrict__ Wr,
    const float* __restrict__ bl,
    bf16* __restrict__ srcb, bf16* __restrict__ tgtb,
    bf16* __restrict__ WHhi, bf16* __restrict__ WHlo,
    bf16* __restrict__ Wrhi, bf16* __restrict__ Wrlo,
    bf16* __restrict__ P2, float* __restrict__ bz) {
    __shared__ float tile[64][65];
    const int bid = blockIdx.x, t = threadIdx.x;
    if (bid < 512) {
        const float* in = (bid < 256) ? Wr : Wk;
        bf16* ohi = (bid < 256) ? Wrhi : P2;
        bf16* olo = (bid < 256) ? Wrlo : nullptr;
        const int b = bid & 255;
        const int tr = b >> 5, tc = b & 31;  // 8 k-blocks x 32 c-blocks of 64x64
#pragma unroll
        for (int q = 0; q < 16; q++) {
            int idx = q * 256 + t, lr = idx >> 6, lc = idx & 63;
            tile[lr][lc] = in[(size_t)(tr * 64 + lr) * 2048 + tc * 64 + lc];
        }
        __syncthreads();
#pragma unroll
        for (int q = 0; q < 16; q++) {
            int idx = q * 256 + t, lr = idx >> 6, lc = idx & 63;
            float v = tile[lc][lr];  // out[tc*64+lr][tr*64+lc] = in[tr*64+lc][tc*64+lr]
            size_t o = (size_t)(tc * 64 + lr) * 512 + tr * 64 + lc;
            bf16 h = (bf16)v;
            ohi[o] = h;
            if (olo) olo[o] = (bf16)(v - (float)h);
        }
    } else if (bid < 520) {
        int c = (bid - 512) * 256 + t;
        float s = bl[c];
        for (int k = 0; k < 512; k++) s += bH[k] * Wr[(size_t)k * 2048 + c];
        bz[c] = s;
    } else {
        const int gt = (bid - 520) * 256 + t, NT = 504 * 256;
        for (int id = gt; id < 1048576; id += NT) srcb[id] = (bf16)src[id];
        for (int id = gt; id < 1048576; id += NT) tgtb[id] = (bf16)tgt[id];
        for (int id = gt; id < 524288; id += NT) {
            float v = WH[id];
            bf16 h = (bf16)v;
            WHhi[id] = h;
            WHlo[id] = (bf16)(v - (float)h);
        }
    }
}

// ---------------- P-matrix builder GEMM (R4-proven body, grid 256) ----------------
__global__ __launch_bounds__(256, 4) void k_gemmP(
    const bf16* __restrict__ Wrhi, const bf16* __restrict__ Wrlo,
    const bf16* __restrict__ WHhi, const bf16* __restrict__ WHlo,
    const float* __restrict__ Wk,
    bf16* __restrict__ P1, bf16* __restrict__ P3,
    bf16* __restrict__ P4, bf16* __restrict__ P5) {
    __shared__ __align__(16) bf16 At[64 * 64];
    __shared__ __align__(16) bf16 Bt[128 * 64];
    const int t = threadIdx.x, w = t >> 6, l = t & 63;
    const int m0 = (blockIdx.x >> 3) * 64, n0 = (blockIdx.x & 7) * 128;
    f32x4 acc[2][4] = {};
    const bf16* Aps[3] = {Wrhi, Wrlo, Wrhi};
    const bf16* Bps[3] = {WHhi, WHhi, WHlo};
    for (int ph = 0; ph < 3; ph++) {
        const bf16* Ap = Aps[ph] + (size_t)m0 * 512;
        const bf16* Bp = Bps[ph] + (size_t)n0 * 512;
        for (int kt = 0; kt < 8; kt++) {
            int k0 = kt * 64;
            __syncthreads();
#pragma unroll
            for (int q = 0; q < 2; q++) {
                int pp = q * 256 + t;
                int r = pp >> 3, c = (pp & 7) ^ (r & 7);
                gl2lds(Ap + (size_t)r * 512 + k0 + c * 8, &At[(q * 256 + w * 64) * 8]);
            }
#pragma unroll
            for (int q = 0; q < 4; q++) {
                int pp = q * 256 + t;
                int r = pp >> 3, c = (pp & 7) ^ (r & 7);
                gl2lds(Bp + (size_t)r * 512 + k0 + c * 8, &Bt[(q * 256 + w * 64) * 8]);
            }
            __syncthreads();
#pragma unroll
            for (int ks = 0; ks < 2; ks++) {
                int c = ks * 4 + (l >> 4);
                bf16x8 af[2], bb[4];
#pragma unroll
                for (int mt = 0; mt < 2; mt++) {
                    int r = (w >> 1) * 32 + mt * 16 + (l & 15);
                    af[mt] = *(const bf16x8*)&At[(r * 8 + (c ^ (r & 7))) * 8];
                }
#pragma unroll
                for (int g = 0; g < 4; g++) {
                    int r = g * 32 + (w & 1) * 16 + (l & 15);
                    bb[g] = *(const bf16x8*)&Bt[(r * 8 + (c ^ (r & 7))) * 8];
                }
#pragma unroll
                for (int mt = 0; mt < 2; mt++)
#pragma unroll
                    for (int g = 0; g < 4; g++)
                        acc[mt][g] = __builtin_amdgcn_mfma_f32_16x16x32_bf16(
                            af[mt], bb[g], acc[mt][g], 0, 0, 0);
            }
        }
    }
    const bool hihalf = (n0 >= 512);
#pragma unroll
    for (int mt = 0; mt < 2; mt++) {
#pragma unroll
        for (int g = 0; g < 4; g++) {
            int np = n0 + g * 32 + (w & 1) * 16 + (l & 15);
#pragma unroll
            for (int r = 0; r < 4; r++) {
                int c = m0 + (w >> 1) * 32 + mt * 16 + ((l >> 4) << 2) + r;
                float v = acc[mt][g][r];
                if (!hihalf) {
                    P4[(size_t)c * 512 + np] = (bf16)v;
                    P1[(size_t)c * 512 + np] = (bf16)(v + Wk[(size_t)np * 2048 + c]);
                } else {
                    int kk = np - 512;
                    P3[(size_t)c * 512 + kk] = (bf16)v;
                    P5[(size_t)c * 512 + kk] = (bf16)(v + Wk[(size_t)kk * 2048 + c]);
                }
            }
        }
    }
}

// ---------------- paired-cell diagonal kernel ----------------
// One K=512 panel phase: stage B in 4-deep LDS rotation (one barrier-drain per
// 4 k-tiles), A direct global->VGPR (cached; coherence via launch boundary).
// A1 == nullptr -> single-cell mode (acc1 untouched).
__device__ __forceinline__ void do_phase(const bf16* __restrict__ A0,
                                         const bf16* __restrict__ A1,
                                         const bf16* __restrict__ Wp, int ch0, int t,
                                         int w, int l, bf16* Bt, f32x4 (*acc0)[4],
                                         f32x4 (*acc1)[4]) {
#pragma unroll 1
    for (int ktg = 0; ktg < 2; ktg++) {
        __syncthreads();  // 4 B-buffers free (previous group's reads done)
#pragma unroll
        for (int q = 0; q < 4; q++) {
            int k0 = (ktg * 4 + q) * 64;
#pragma unroll
            for (int io = 0; io < 4; io++) {
                int pp = io * 256 + t;
                int r = pp >> 3, c = (pp & 7) ^ (r & 7), g = r >> 5;
                gl2lds(Wp + (size_t)(g * 512 + ch0 + (r & 31)) * 512 + k0 + c * 8,
                       &Bt[(q * 1024 + io * 256 + w * 64) * 8]);
            }
        }
        __syncthreads();  // vmcnt(0) drain: all 4 panels ready
#pragma unroll
        for (int q = 0; q < 4; q++) {
            int k0 = (ktg * 4 + q) * 64;
            bf16x8 a0[2][2], a1[2][2];
#pragma unroll
            for (int ks = 0; ks < 2; ks++)
#pragma unroll
                for (int mt = 0; mt < 2; mt++) {
                    int r = (w >> 1) * 32 + mt * 16 + (l & 15);
                    size_t off = (size_t)r * 512 + k0 + ks * 32 + (l >> 4) * 8;
                    a0[ks][mt] = *(const bf16x8*)(A0 + off);
                    if (A1) a1[ks][mt] = *(const bf16x8*)(A1 + off);
                }
#pragma unroll
            for (int ks = 0; ks < 2; ks++) {
                int cq = ks * 4 + (l >> 4);
#pragma unroll
                for (int g = 0; g < 4; g++) {
                    int r = g * 32 + (w & 1) * 16 + (l & 15);
                    bf16x8 bb = *(const bf16x8*)&Bt[(q * 1024 + r * 8 + (cq ^ (r & 7))) * 8];
#pragma unroll
                    for (int mt = 0; mt < 2; mt++) {
                        acc0[mt][g] = __builtin_amdgcn_mfma_f32_16x16x32_bf16(
                            a0[ks][mt], bb, acc0[mt][g], 0, 0, 0);
                        if (A1)
                            acc1[mt][g] = __builtin_amdgcn_mfma_f32_16x16x32_bf16(
                                a1[ks][mt], bb, acc1[mt][g], 0, 0, 0);
                    }
                }
            }
        }
    }
}

__device__ __forceinline__ int build_panels(int i, int d, int side,
                                            const bf16* srcb, const bf16* tgtb,
                                            const bf16* shR, const bf16* thR,
                                            const bf16* P1, const bf16* P2,
                                            const bf16* P3, const bf16* P4,
                                            const bf16* P5, const bf16** A,
                                            const bf16** W) {
    const int j = d - i;
    const size_t stI = (size_t)i * 32768, stJ = (size_t)j * 32768;
    int nh = 0;
    if (side == 0) {  // z_s
        A[nh] = (j == 0 ? srcb : shR) + stI;
        W[nh] = (j == 0 ? P2 : P1);
        nh++;
        if (i > 0) { A[nh] = thR + stJ; W[nh] = P3; nh++; }
    } else {  // z_t
        if (j > 0) { A[nh] = shR + stI; W[nh] = P4; nh++; }
        A[nh] = (i == 0 ? tgtb : thR) + stJ;
        W[nh] = (i == 0 ? P2 : P5);
        nh++;
    }
    return nh;
}

__global__ __launch_bounds__(256, 2) void k_diag2(
    int d, int i_lo, int i_hi,
    const bf16* __restrict__ srcb, const bf16* __restrict__ tgtb,
    const bf16* __restrict__ P1, const bf16* __restrict__ P2,
    const bf16* __restrict__ P3, const bf16* __restrict__ P4,
    const bf16* __restrict__ P5,
    const float* __restrict__ bz,
    const bf16* __restrict__ shR, bf16* __restrict__ shW,
    const bf16* __restrict__ thR, bf16* __restrict__ thW,
    float* __restrict__ sc, float* __restrict__ tc,
    float* __restrict__ out) {
    __shared__ __align__(16) bf16 Bt[4 * 128 * 64];  // 64 KB: 4-deep B rotation
    const int t = threadIdx.x, w = t >> 6, l = t & 63;
    const int pairI = blockIdx.x >> 5, sub = blockIdx.x & 31;
    const int side = sub >> 4, ch0 = (sub & 15) << 5;
    const int ia = i_lo + pairI * 2;
    const int ib = ia + 1;
    const bool v1 = (ib <= i_hi);

    const bf16 *A0[2], *W0[2], *A1[2], *W1[2];
    const int nh0 = build_panels(ia, d, side, srcb, tgtb, shR, thR, P1, P2, P3, P4, P5, A0, W0);
    int nh1 = 0;
    if (v1) nh1 = build_panels(ib, d, side, srcb, tgtb, shR, thR, P1, P2, P3, P4, P5, A1, W1);
    const bool share = v1 && (nh0 == nh1) && (W0[0] == W1[0]) && (nh0 < 2 || W0[1] == W1[1]);

    f32x4 acc0[2][4] = {}, acc1[2][4] = {};
    if (share) {
        for (int hh = 0; hh < nh0; hh++)
            do_phase(A0[hh], A1[hh], W0[hh], ch0, t, w, l, Bt, acc0, acc1);
    } else {
        for (int hh = 0; hh < nh0; hh++)
            do_phase(A0[hh], nullptr, W0[hh], ch0, t, w, l, Bt, acc0, acc0);
        if (v1)
            for (int hh = 0; hh < nh1; hh++)
                do_phase(A1[hh], nullptr, W1[hh], ch0, t, w, l, Bt, acc1, acc1);
    }

    // in-register gate epilogue (R1-proven), per cell
    const int h = ch0 + (w & 1) * 16 + (l & 15);
    float bzv[4];
#pragma unroll
    for (int g = 0; g < 4; g++) bzv[g] = bz[g * 512 + h];
    const int ncell = v1 ? 2 : 1;
    for (int s = 0; s < ncell; s++) {
        const int i = ia + s, j = d - i;
        const size_t stI = (size_t)i * 32768, stJ = (size_t)j * 32768;
        f32x4(*acc)[4] = s ? acc1 : acc0;
#pragma unroll
        for (int mt = 0; mt < 2; mt++) {
#pragma unroll
            for (int r = 0; r < 4; r++) {
                int b = (w >> 1) * 32 + mt * 16 + ((l >> 4) << 2) + r;
                float zi = acc[mt][0][r] + bzv[0];
                float zf = acc[mt][1][r] + bzv[1];
                float zg = acc[mt][2][r] + bzv[2];
                float zo = acc[mt][3][r] + bzv[3];
                if (side == 0) {
                    size_t off = stI + (size_t)b * 512 + h;
                    float cold = (j == 0) ? 0.f : sc[off];
                    float c2 = sigm(zf) * cold + sigm(zi) * tanh_(zg);
                    float h2 = sigm(zo) * tanh_(c2);
                    sc[off] = c2;
                    shW[off] = (bf16)h2;
                    if (j == 31) out[off] = h2;  // source_out[i]
                } else {
                    size_t off = stJ + (size_t)b * 512 + h;
                    float cold = (i == 0) ? 0.f : tc[off];
                    float c2 = sigm(zf) * cold + sigm(zi) * tanh_(zg);
                    float h2 = sigm(zo) * tanh_(c2);
                    tc[off] = c2;
                    thW[off] = (bf16)h2;
                    if (i == 31) out[1048576 + off] = h2;  // t_final[0][j]
                }
            }
        }
    }
}

// ---------------- host ----------------

extern "C" void kernel_launch(void* const* d_in, const int* in_sizes, int n_in,
                              void* d_out, int out_size, void* d_ws, size_t ws_size,
                              hipStream_t stream) {
    char* w = (char*)d_ws;
    const size_t MB = 1u << 20;
    const float* src = (const float*)d_in[0];
    const float* tgt = (const float*)d_in[1];
    const float* WH = (const float*)d_in[2];
    const float* bH = (const float*)d_in[3];
    const float* Wk = (const float*)d_in[4];
    const float* Wr = (const float*)d_in[5];
    const float* bl = (const float*)d_in[6];
    float* out = (float*)d_out;

    bf16* srcb = (bf16*)(w + 0 * MB);    // [32][64][512]
    bf16* tgtb = (bf16*)(w + 2 * MB);
    bf16* WHhi = (bf16*)(w + 4 * MB);    // [1024][512]
    bf16* WHlo = (bf16*)(w + 5 * MB);
    bf16* Wrhi = (bf16*)(w + 6 * MB);    // [2048][512] (W_rec^T)
    bf16* Wrlo = (bf16*)(w + 8 * MB);
    bf16* P1 = (bf16*)(w + 10 * MB);     // Wk^T + WHW_hi^T
    bf16* P2 = (bf16*)(w + 12 * MB);     // Wk^T
    bf16* P3 = (bf16*)(w + 14 * MB);     // WHW_lo^T
    bf16* P4 = (bf16*)(w + 16 * MB);     // WHW_hi^T
    bf16* P5 = (bf16*)(w + 18 * MB);     // Wk^T + WHW_lo^T
    float* bz = (float*)(w + 20 * MB);   // [2048]
    bf16* sh = (bf16*)(w + 21 * MB);     // [2][32][64][512] double-buffered
    bf16* th = (bf16*)(w + 25 * MB);
    float* sc = (float*)(w + 29 * MB);   // [32][64][512] fp32
    float* tc = (float*)(w + 33 * MB);   // end: 37 MB

    k_prep<<<1024, BLK, 0, stream>>>(src, tgt, WH, bH, Wk, Wr, bl, srcb, tgtb,
                                     WHhi, WHlo, Wrhi, Wrlo, P2, bz);
    k_gemmP<<<256, BLK, 0, stream>>>(Wrhi, Wrlo, WHhi, WHlo, Wk, P1, P3, P4, P5);

    for (int d = 0; d < 63; d++) {
        int i_lo = d > 31 ? d - 31 : 0;
        int i_hi = d < 31 ? d : 31;
        int Kd = i_hi - i_lo + 1;
        int nPair = (Kd + 1) >> 1;
        const bf16* shR = sh + (size_t)(d & 1) * 1048576;
        bf16* shW = sh + (size_t)((d + 1) & 1) * 1048576;
        const bf16* thR = th + (size_t)(d & 1) * 1048576;
        bf16* thW = th + (size_t)((d + 1) & 1) * 1048576;
        k_diag2<<<nPair * 32, BLK, 0, stream>>>(d, i_lo, i_hi, srcb, tgtb, P1, P2, P3,
                                                P4, P5, bz, shR, shW, thR, thW, sc, tc,
                                                out);
    }
}

// Round 7
// 1409.700 us; speedup vs baseline: 6.1696x; 1.7823x over previous
//
#include <hip/hip_runtime.h>

#define BLK 256

typedef __bf16 bf16;
typedef __bf16 bf16x8 __attribute__((ext_vector_type(8)));
typedef float f32x4 __attribute__((ext_vector_type(4)));

__device__ __forceinline__ float sigm(float x) { return 1.f / (1.f + __expf(-x)); }
__device__ __forceinline__ float tanh_(float x) {
    x = fminf(fmaxf(x, -15.f), 15.f);
    float e = __expf(2.f * x);
    return (e - 1.f) / (e + 1.f);
}

// async 16B global->LDS; lds dest is wave-uniform base (+ lane*16 implicit)
__device__ __forceinline__ void gl2lds(const bf16* g, bf16* l) {
    __builtin_amdgcn_global_load_lds((const __attribute__((address_space(1))) void*)g,
                                     (__attribute__((address_space(3))) void*)l, 16, 0, 0);
}

// ---------------- fused prep: tiled transposes + casts + bz ----------------
__global__ __launch_bounds__(256) void k_prep(
    const float* __restrict__ src, const float* __restrict__ tgt,
    const float* __restrict__ WH, const float* __restrict__ bH,
    const float* __restrict__ Wk, const float* __restrict__ Wr,
    const float* __restrict__ bl,
    bf16* __restrict__ srcb, bf16* __restrict__ tgtb,
    bf16* __restrict__ WHhi, bf16* __restrict__ WHlo,
    bf16* __restrict__ Wrhi, bf16* __restrict__ Wrlo,
    bf16* __restrict__ P2, float* __restrict__ bz) {
    __shared__ float tile[64][65];
    const int bid = blockIdx.x, t = threadIdx.x;
    if (bid < 512) {
        const float* in = (bid < 256) ? Wr : Wk;
        bf16* ohi = (bid < 256) ? Wrhi : P2;
        bf16* olo = (bid < 256) ? Wrlo : nullptr;
        const int b = bid & 255;
        const int tr = b >> 5, tc = b & 31;  // 8 k-blocks x 32 c-blocks of 64x64
#pragma unroll
        for (int q = 0; q < 16; q++) {
            int idx = q * 256 + t, lr = idx >> 6, lc = idx & 63;
            tile[lr][lc] = in[(size_t)(tr * 64 + lr) * 2048 + tc * 64 + lc];
        }
        __syncthreads();
#pragma unroll
        for (int q = 0; q < 16; q++) {
            int idx = q * 256 + t, lr = idx >> 6, lc = idx & 63;
            float v = tile[lc][lr];
            size_t o = (size_t)(tc * 64 + lr) * 512 + tr * 64 + lc;
            bf16 h = (bf16)v;
            ohi[o] = h;
            if (olo) olo[o] = (bf16)(v - (float)h);
        }
    } else if (bid < 520) {
        int c = (bid - 512) * 256 + t;
        float s = bl[c];
        for (int k = 0; k < 512; k++) s += bH[k] * Wr[(size_t)k * 2048 + c];
        bz[c] = s;
    } else {
        const int gt = (bid - 520) * 256 + t, NT = 504 * 256;
        for (int id = gt; id < 1048576; id += NT) srcb[id] = (bf16)src[id];
        for (int id = gt; id < 1048576; id += NT) tgtb[id] = (bf16)tgt[id];
        for (int id = gt; id < 524288; id += NT) {
            float v = WH[id];
            bf16 h = (bf16)v;
            WHhi[id] = h;
            WHlo[id] = (bf16)(v - (float)h);
        }
    }
}

// ---------------- P-matrix builder GEMM (R4/R6-proven body, grid 256) ----------------
__global__ __launch_bounds__(256, 4) void k_gemmP(
    const bf16* __restrict__ Wrhi, const bf16* __restrict__ Wrlo,
    const bf16* __restrict__ WHhi, const bf16* __restrict__ WHlo,
    const float* __restrict__ Wk,
    bf16* __restrict__ P1, bf16* __restrict__ P3,
    bf16* __restrict__ P4, bf16* __restrict__ P5) {
    __shared__ __align__(16) bf16 At[64 * 64];
    __shared__ __align__(16) bf16 Bt[128 * 64];
    const int t = threadIdx.x, w = t >> 6, l = t & 63;
    const int m0 = (blockIdx.x >> 3) * 64, n0 = (blockIdx.x & 7) * 128;
    f32x4 acc[2][4] = {};
    const bf16* Aps[3] = {Wrhi, Wrlo, Wrhi};
    const bf16* Bps[3] = {WHhi, WHhi, WHlo};
    for (int ph = 0; ph < 3; ph++) {
        const bf16* Ap = Aps[ph] + (size_t)m0 * 512;
        const bf16* Bp = Bps[ph] + (size_t)n0 * 512;
        for (int kt = 0; kt < 8; kt++) {
            int k0 = kt * 64;
            __syncthreads();
#pragma unroll
            for (int q = 0; q < 2; q++) {
                int pp = q * 256 + t;
                int r = pp >> 3, c = (pp & 7) ^ (r & 7);
                gl2lds(Ap + (size_t)r * 512 + k0 + c * 8, &At[(q * 256 + w * 64) * 8]);
            }
#pragma unroll
            for (int q = 0; q < 4; q++) {
                int pp = q * 256 + t;
                int r = pp >> 3, c = (pp & 7) ^ (r & 7);
                gl2lds(Bp + (size_t)r * 512 + k0 + c * 8, &Bt[(q * 256 + w * 64) * 8]);
            }
            __syncthreads();
#pragma unroll
            for (int ks = 0; ks < 2; ks++) {
                int c = ks * 4 + (l >> 4);
                bf16x8 af[2], bb[4];
#pragma unroll
                for (int mt = 0; mt < 2; mt++) {
                    int r = (w >> 1) * 32 + mt * 16 + (l & 15);
                    af[mt] = *(const bf16x8*)&At[(r * 8 + (c ^ (r & 7))) * 8];
                }
#pragma unroll
                for (int g = 0; g < 4; g++) {
                    int r = g * 32 + (w & 1) * 16 + (l & 15);
                    bb[g] = *(const bf16x8*)&Bt[(r * 8 + (c ^ (r & 7))) * 8];
                }
#pragma unroll
                for (int mt = 0; mt < 2; mt++)
#pragma unroll
                    for (int g = 0; g < 4; g++)
                        acc[mt][g] = __builtin_amdgcn_mfma_f32_16x16x32_bf16(
                            af[mt], bb[g], acc[mt][g], 0, 0, 0);
            }
        }
    }
    const bool hihalf = (n0 >= 512);
#pragma unroll
    for (int mt = 0; mt < 2; mt++) {
#pragma unroll
        for (int g = 0; g < 4; g++) {
            int np = n0 + g * 32 + (w & 1) * 16 + (l & 15);
#pragma unroll
            for (int r = 0; r < 4; r++) {
                int c = m0 + (w >> 1) * 32 + mt * 16 + ((l >> 4) << 2) + r;
                float v = acc[mt][g][r];
                if (!hihalf) {
                    P4[(size_t)c * 512 + np] = (bf16)v;
                    P1[(size_t)c * 512 + np] = (bf16)(v + Wk[(size_t)np * 2048 + c]);
                } else {
                    int kk = np - 512;
                    P3[(size_t)c * 512 + kk] = (bf16)v;
                    P5[(size_t)c * 512 + kk] = (bf16)(v + Wk[(size_t)kk * 2048 + c]);
                }
            }
        }
    }
}

// ---------------- per-diagonal fused GEMM + LSTM gates, K-tile=128 ----------------
// R2 structure with halved drain-round count: 8 rounds interior (vs 16).
// LDS 48 KB single-buffered: A 64x128 (16 KB) + B 128x128 (32 KB), 16-chunk
// XOR swizzle (c ^ (r&15)) -> <=2-way ds_read_b128 aliasing (free).
__global__ __launch_bounds__(256, 3) void k_diag3(
    int d, int i_lo,
    const bf16* __restrict__ srcb, const bf16* __restrict__ tgtb,
    const bf16* __restrict__ P1, const bf16* __restrict__ P2,
    const bf16* __restrict__ P3, const bf16* __restrict__ P4,
    const bf16* __restrict__ P5,
    const float* __restrict__ bz,
    const bf16* __restrict__ shR, bf16* __restrict__ shW,
    const bf16* __restrict__ thR, bf16* __restrict__ thW,
    float* __restrict__ sc, float* __restrict__ tc,
    float* __restrict__ out) {
    __shared__ __align__(16) bf16 At[64 * 128];   // 16 KB
    __shared__ __align__(16) bf16 Bt[128 * 128];  // 32 KB
    const int t = threadIdx.x, w = t >> 6, l = t & 63;
    const int cell = blockIdx.x >> 5, sub = blockIdx.x & 31;
    const int side = sub >> 4, ch0 = (sub & 15) << 5;
    const int i = i_lo + cell, j = d - i;
    const size_t stI = (size_t)i * 32768, stJ = (size_t)j * 32768;

    const bf16* Ah[2];
    const bf16* Wh[2];
    int nh = 0;
    if (side == 0) {  // z_s
        Ah[nh] = (j == 0 ? srcb : shR) + stI;
        Wh[nh] = (j == 0 ? P2 : P1);
        nh++;
        if (i > 0) { Ah[nh] = thR + stJ; Wh[nh] = P3; nh++; }
    } else {  // z_t
        if (j > 0) { Ah[nh] = shR + stI; Wh[nh] = P4; nh++; }
        Ah[nh] = (i == 0 ? tgtb : thR) + stJ;
        Wh[nh] = (i == 0 ? P2 : P5);
        nh++;
    }

    f32x4 acc[2][4] = {};
    for (int hh = 0; hh < nh; hh++) {
        const bf16* Ap = Ah[hh];
        const bf16* Wp = Wh[hh];
#pragma unroll 1
        for (int kt = 0; kt < 4; kt++) {
            int k0 = kt * 128;
            __syncthreads();
            // A tile: 64 rows x 16 chunks = 1024 chunks, 4 issues
#pragma unroll
            for (int q = 0; q < 4; q++) {
                int pp = q * 256 + t;
                int r = pp >> 4, c = (pp & 15) ^ (r & 15);
                gl2lds(Ap + (size_t)r * 512 + k0 + c * 8, &At[(q * 256 + w * 64) * 8]);
            }
            // B tile: 128 rows x 16 chunks = 2048 chunks, 8 issues
#pragma unroll
            for (int q = 0; q < 8; q++) {
                int pp = q * 256 + t;
                int r = pp >> 4, c = (pp & 15) ^ (r & 15);
                int g = r >> 5;
                gl2lds(Wp + (size_t)(g * 512 + ch0 + (r & 31)) * 512 + k0 + c * 8,
                       &Bt[(q * 256 + w * 64) * 8]);
            }
            __syncthreads();
#pragma unroll
            for (int ks = 0; ks < 4; ks++) {
                int cq = ks * 4 + (l >> 4);
                bf16x8 af[2], bb[4];
#pragma unroll
                for (int mt = 0; mt < 2; mt++) {
                    int r = (w >> 1) * 32 + mt * 16 + (l & 15);
                    af[mt] = *(const bf16x8*)&At[(r * 16 + (cq ^ (r & 15))) * 8];
                }
#pragma unroll
                for (int g = 0; g < 4; g++) {
                    int r = g * 32 + (w & 1) * 16 + (l & 15);
                    bb[g] = *(const bf16x8*)&Bt[(r * 16 + (cq ^ (r & 15))) * 8];
                }
#pragma unroll
                for (int mt = 0; mt < 2; mt++)
#pragma unroll
                    for (int g = 0; g < 4; g++)
                        acc[mt][g] = __builtin_amdgcn_mfma_f32_16x16x32_bf16(
                            af[mt], bb[g], acc[mt][g], 0, 0, 0);
            }
        }
    }

    // in-register gate epilogue: lane holds all 4 gates of its (b, h)
    const int h = ch0 + (w & 1) * 16 + (l & 15);
    float bzv[4];
#pragma unroll
    for (int g = 0; g < 4; g++) bzv[g] = bz[g * 512 + h];
#pragma unroll
    for (int mt = 0; mt < 2; mt++) {
#pragma unroll
        for (int r = 0; r < 4; r++) {
            int b = (w >> 1) * 32 + mt * 16 + ((l >> 4) << 2) + r;
            float zi = acc[mt][0][r] + bzv[0];
            float zf = acc[mt][1][r] + bzv[1];
            float zg = acc[mt][2][r] + bzv[2];
            float zo = acc[mt][3][r] + bzv[3];
            if (side == 0) {
                size_t off = stI + (size_t)b * 512 + h;
                float cold = (j == 0) ? 0.f : sc[off];
                float c2 = sigm(zf) * cold + sigm(zi) * tanh_(zg);
                float h2 = sigm(zo) * tanh_(c2);
                sc[off] = c2;
                shW[off] = (bf16)h2;
                if (j == 31) out[off] = h2;  // source_out[i]
            } else {
                size_t off = stJ + (size_t)b * 512 + h;
                float cold = (i == 0) ? 0.f : tc[off];
                float c2 = sigm(zf) * cold + sigm(zi) * tanh_(zg);
                float h2 = sigm(zo) * tanh_(c2);
                tc[off] = c2;
                thW[off] = (bf16)h2;
                if (i == 31) out[1048576 + off] = h2;  // t_final[0][j]
            }
        }
    }
}

// ---------------- host ----------------

extern "C" void kernel_launch(void* const* d_in, const int* in_sizes, int n_in,
                              void* d_out, int out_size, void* d_ws, size_t ws_size,
                              hipStream_t stream) {
    char* w = (char*)d_ws;
    const size_t MB = 1u << 20;
    const float* src = (const float*)d_in[0];
    const float* tgt = (const float*)d_in[1];
    const float* WH = (const float*)d_in[2];
    const float* bH = (const float*)d_in[3];
    const float* Wk = (const float*)d_in[4];
    const float* Wr = (const float*)d_in[5];
    const float* bl = (const float*)d_in[6];
    float* out = (float*)d_out;

    bf16* srcb = (bf16*)(w + 0 * MB);    // [32][64][512]
    bf16* tgtb = (bf16*)(w + 2 * MB);
    bf16* WHhi = (bf16*)(w + 4 * MB);    // [1024][512]
    bf16* WHlo = (bf16*)(w + 5 * MB);
    bf16* Wrhi = (bf16*)(w + 6 * MB);    // [2048][512] (W_rec^T)
    bf16* Wrlo = (bf16*)(w + 8 * MB);
    bf16* P1 = (bf16*)(w + 10 * MB);     // Wk^T + WHW_hi^T
    bf16* P2 = (bf16*)(w + 12 * MB);     // Wk^T
    bf16* P3 = (bf16*)(w + 14 * MB);     // WHW_lo^T
    bf16* P4 = (bf16*)(w + 16 * MB);     // WHW_hi^T
    bf16* P5 = (bf16*)(w + 18 * MB);     // Wk^T + WHW_lo^T
    float* bz = (float*)(w + 20 * MB);   // [2048]
    bf16* sh = (bf16*)(w + 21 * MB);     // [2][32][64][512] double-buffered
    bf16* th = (bf16*)(w + 25 * MB);
    float* sc = (float*)(w + 29 * MB);   // [32][64][512] fp32
    float* tc = (float*)(w + 33 * MB);   // end: 37 MB

    k_prep<<<1024, BLK, 0, stream>>>(src, tgt, WH, bH, Wk, Wr, bl, srcb, tgtb,
                                     WHhi, WHlo, Wrhi, Wrlo, P2, bz);
    k_gemmP<<<256, BLK, 0, stream>>>(Wrhi, Wrlo, WHhi, WHlo, Wk, P1, P3, P4, P5);

    for (int d = 0; d < 63; d++) {
        int i_lo = d > 31 ? d - 31 : 0;
        int i_hi = d < 31 ? d : 31;
        int Kd = i_hi - i_lo + 1;
        const bf16* shR = sh + (size_t)(d & 1) * 1048576;
        bf16* shW = sh + (size_t)((d + 1) & 1) * 1048576;
        const bf16* thR = th + (size_t)(d & 1) * 1048576;
        bf16* thW = th + (size_t)((d + 1) & 1) * 1048576;
        k_diag3<<<Kd * 32, BLK, 0, stream>>>(d, i_lo, srcb, tgtb, P1, P2, P3, P4, P5,
                                             bz, shR, shW, thR, thW, sc, tc, out);
    }
}